// Round 1
// baseline (329.826 us; speedup 1.0000x reference)
//
#include <hip/hip_runtime.h>
#include <hip/hip_bf16.h>

#define IN_CH 4096
#define OUT_CH 11008
#define QBLK 64

#define BM 128
#define BN 64
#define BK 64
#define KCHUNKS (IN_CH / BK)   // 64
#define XCONV_BLOCKS 16

typedef short bf16x8 __attribute__((ext_vector_type(8)));
typedef float f32x4 __attribute__((ext_vector_type(4)));

#define GLOBAL_AS __attribute__((address_space(1)))
#define LDS_AS __attribute__((address_space(3)))

__device__ inline unsigned short f2bf(float f) {
    union { __hip_bfloat16 h; unsigned short u; } cv;
    cv.h = __float2bfloat16(f);
    return cv.u;
}

// ---------------------------------------------------------------------------
// Kernel 1: LPBQ quantize-dequantize of weight -> bf16, plus x -> bf16.
// One 256-thread block per weight row (blocks [0, OUT_CH)).
// Blocks [OUT_CH, OUT_CH+16) convert x.
// Row = 4096 el = 4 passes of (256 thr x float4). 64 quant-blocks of 64 el;
// one quant-block = 16 consecutive lanes' float4s (within one wave).
// ---------------------------------------------------------------------------
__global__ __launch_bounds__(256) void quant_kernel(
        const float* __restrict__ w, const float* __restrict__ x,
        unsigned short* __restrict__ wq, unsigned short* __restrict__ xq) {
    const int tid = threadIdx.x;

    if (blockIdx.x >= OUT_CH) {
        // ---- x fp32 -> bf16 (128*4096 = 524288 el = 131072 float4) ----
        const int bx = blockIdx.x - OUT_CH;
        const float4* x4 = (const float4*)x;
        for (int it = 0; it < 32; ++it) {
            const int g = bx * 8192 + it * 256 + tid;
            float4 v = x4[g];
            ushort4 o;
            o.x = f2bf(v.x); o.y = f2bf(v.y); o.z = f2bf(v.z); o.w = f2bf(v.w);
            ((ushort4*)xq)[g] = o;
        }
        return;
    }

    const float* wrow = w + (size_t)blockIdx.x * IN_CH;
    unsigned short* orow = wq + (size_t)blockIdx.x * IN_CH;

    __shared__ float s1_lds[64];
    __shared__ float s2_lds;

    float4 v[4];
    const int lane16 = tid & 15;

    // Pass A: per-64-block max|.| -> s1
    for (int p = 0; p < 4; ++p) {
        v[p] = ((const float4*)wrow)[p * 256 + tid];
        float m = fmaxf(fmaxf(fabsf(v[p].x), fabsf(v[p].y)),
                        fmaxf(fabsf(v[p].z), fabsf(v[p].w)));
        m = fmaxf(m, __shfl_xor(m, 1));
        m = fmaxf(m, __shfl_xor(m, 2));
        m = fmaxf(m, __shfl_xor(m, 4));
        m = fmaxf(m, __shfl_xor(m, 8));
        if (lane16 == 0)
            s1_lds[p * 16 + (tid >> 4)] = fmaxf(m * (1.0f / 7.0f), 1e-8f);
    }
    __syncthreads();

    // Pass B: s2 = clip(max_b s1 / 15, 1e-8) (wave 0 reduces the 64 s1's)
    if (tid < 64) {
        float m = s1_lds[tid];
        m = fmaxf(m, __shfl_xor(m, 1));
        m = fmaxf(m, __shfl_xor(m, 2));
        m = fmaxf(m, __shfl_xor(m, 4));
        m = fmaxf(m, __shfl_xor(m, 8));
        m = fmaxf(m, __shfl_xor(m, 16));
        m = fmaxf(m, __shfl_xor(m, 32));
        if (tid == 0) s2_lds = fmaxf(m * (1.0f / 15.0f), 1e-8f);
    }
    __syncthreads();
    const float s2 = s2_lds;

    // Pass C: requantize exactly as reference (fp32 div + rintf = round-half-even)
    for (int p = 0; p < 4; ++p) {
        const float s1 = s1_lds[p * 16 + (tid >> 4)];
        const float s1q = fminf(fmaxf(rintf(s1 / s2), 0.0f), 15.0f);
        const float s1r = s1q * s2;
        ushort4 o;
        o.x = f2bf(fminf(fmaxf(rintf(v[p].x / s1r), -8.0f), 7.0f) * s1r);
        o.y = f2bf(fminf(fmaxf(rintf(v[p].y / s1r), -8.0f), 7.0f) * s1r);
        o.z = f2bf(fminf(fmaxf(rintf(v[p].z / s1r), -8.0f), 7.0f) * s1r);
        o.w = f2bf(fminf(fmaxf(rintf(v[p].w / s1r), -8.0f), 7.0f) * s1r);
        ((ushort4*)orow)[p * 256 + tid] = o;
    }
}

// ---------------------------------------------------------------------------
// Kernel 2: bf16 GEMM, C[m,n] = sum_k A[m,k]*B[n,k] + bias[n]  (gemm_bt)
// A = x_bf16 (128 x 4096), B = w_bf16 (11008 x 4096), C fp32 (128 x 11008).
// BM=128 (all of M), BN=64 -> 172 blocks. 4 waves in 2x2; each wave owns a
// 64x32 output patch = 4x2 grid of 16x16 MFMA tiles. global_load_lds w=16.
// ---------------------------------------------------------------------------
__global__ __launch_bounds__(256) void gemm_kernel(
        const unsigned short* __restrict__ A, const unsigned short* __restrict__ B,
        const float* __restrict__ bias, float* __restrict__ C) {
    __shared__ __align__(16) unsigned short ldsA[BM * BK];  // [m][k], 16 KB
    __shared__ __align__(16) unsigned short ldsB[BN * BK];  // [n][k], 8 KB

    const int tid = threadIdx.x;
    const int w = tid >> 6;      // wave 0..3
    const int l = tid & 63;      // lane
    const int wm = w >> 1;       // 0..1 : which 64-row half of M
    const int wn = w & 1;        // 0..1 : which 32-col half of N-tile
    const int n0 = blockIdx.x * BN;

    const int r8 = l >> 3;       // staging: row within 8-row group
    const int sg = l & 7;        // staging: 16B segment within 128B row

    f32x4 acc[4][2] = {};

    const int lane15 = l & 15;
    const int quad = l >> 4;

    for (int kc = 0; kc < KCHUNKS; ++kc) {
        const int k0 = kc * BK;

        // ---- stage A tile: 128 rows x 128B, 4 block-wide issues ----
        for (int i = 0; i < 4; ++i) {
            const int r = i * 32 + w * 8 + r8;
            const unsigned short* gp = A + (size_t)r * IN_CH + k0 + sg * 8;
            LDS_AS unsigned short* lp =
                (LDS_AS unsigned short*)&ldsA[(i * 32 + w * 8) * BK];
            __builtin_amdgcn_global_load_lds((const GLOBAL_AS void*)gp,
                                             (LDS_AS void*)lp, 16, 0, 0);
        }
        // ---- stage B tile: 64 rows x 128B, 2 block-wide issues ----
        for (int j = 0; j < 2; ++j) {
            const int r = j * 32 + w * 8 + r8;
            const unsigned short* gp = B + (size_t)(n0 + r) * IN_CH + k0 + sg * 8;
            LDS_AS unsigned short* lp =
                (LDS_AS unsigned short*)&ldsB[(j * 32 + w * 8) * BK];
            __builtin_amdgcn_global_load_lds((const GLOBAL_AS void*)gp,
                                             (LDS_AS void*)lp, 16, 0, 0);
        }
        asm volatile("s_waitcnt vmcnt(0)" ::: "memory");
        __syncthreads();

        // ---- MFMA over the 64-deep chunk (two 32-deep steps) ----
        for (int kk = 0; kk < 2; ++kk) {
            bf16x8 af[4], bfv[2];
            const int ko = kk * 32 + quad * 8;
            for (int i = 0; i < 4; ++i)
                af[i] = *(const bf16x8*)&ldsA[(wm * 64 + i * 16 + lane15) * BK + ko];
            for (int j = 0; j < 2; ++j)
                bfv[j] = *(const bf16x8*)&ldsB[(wn * 32 + j * 16 + lane15) * BK + ko];
            for (int i = 0; i < 4; ++i)
                for (int j = 0; j < 2; ++j)
                    acc[i][j] = __builtin_amdgcn_mfma_f32_16x16x32_bf16(
                        af[i], bfv[j], acc[i][j], 0, 0, 0);
        }
        __syncthreads();
    }

    // ---- epilogue: C/D layout col=lane&15, row=quad*4+reg ----
    const int m_base = wm * 64 + quad * 4;
    const int n_base = n0 + wn * 32 + lane15;
    for (int j = 0; j < 2; ++j) {
        const float bv = bias[n_base + j * 16];
        for (int i = 0; i < 4; ++i) {
            const int m = m_base + i * 16;
            float* cp = C + (size_t)m * OUT_CH + n_base + j * 16;
            cp[0 * OUT_CH] = acc[i][j][0] + bv;
            cp[1 * OUT_CH] = acc[i][j][1] + bv;
            cp[2 * OUT_CH] = acc[i][j][2] + bv;
            cp[3 * OUT_CH] = acc[i][j][3] + bv;
        }
    }
}

extern "C" void kernel_launch(void* const* d_in, const int* in_sizes, int n_in,
                              void* d_out, int out_size, void* d_ws, size_t ws_size,
                              hipStream_t stream) {
    const float* x = (const float*)d_in[0];       // (1,128,4096) fp32
    const float* weight = (const float*)d_in[1];  // (11008,4096) fp32
    const float* bias = (const float*)d_in[2];    // (11008,) fp32
    float* out = (float*)d_out;                   // (1,128,11008) fp32

    unsigned short* wsW = (unsigned short*)d_ws;                  // 90.2 MB bf16 w_recon
    unsigned short* wsX = wsW + (size_t)OUT_CH * IN_CH;           // 1 MB bf16 x

    quant_kernel<<<OUT_CH + XCONV_BLOCKS, 256, 0, stream>>>(weight, x, wsW, wsX);
    gemm_kernel<<<OUT_CH / BN, 256, 0, stream>>>(wsX, wsW, bias, out);
}

// Round 2
// 300.758 us; speedup vs baseline: 1.0966x; 1.0966x over previous
//
#include <hip/hip_runtime.h>
#include <hip/hip_bf16.h>

#define IN_CH 4096
#define OUT_CH 11008
#define QBLK 64

#define BM 128
#define BN 64
#define BK 64
#define KCHUNKS (IN_CH / BK)          // 64
#define KSPLIT 4
#define SPLIT_CHUNKS (KCHUNKS / KSPLIT) // 16
#define NTILES (OUT_CH / BN)          // 172
#define XCONV_BLOCKS 16

typedef short bf16x8 __attribute__((ext_vector_type(8)));
typedef float f32x4 __attribute__((ext_vector_type(4)));

#define GLOBAL_AS __attribute__((address_space(1)))
#define LDS_AS __attribute__((address_space(3)))

__device__ inline unsigned short f2bf(float f) {
    union { __hip_bfloat16 h; unsigned short u; } cv;
    cv.h = __float2bfloat16(f);
    return cv.u;
}

// ---------------------------------------------------------------------------
// Kernel 1: LPBQ quantize-dequantize of weight -> bf16, plus x -> bf16.
// One 256-thread block per weight row. Blocks [OUT_CH, OUT_CH+16) convert x.
// ---------------------------------------------------------------------------
__global__ __launch_bounds__(256) void quant_kernel(
        const float* __restrict__ w, const float* __restrict__ x,
        unsigned short* __restrict__ wq, unsigned short* __restrict__ xq) {
    const int tid = threadIdx.x;

    if (blockIdx.x >= OUT_CH) {
        // ---- x fp32 -> bf16 (128*4096 el = 131072 float4) ----
        const int bx = blockIdx.x - OUT_CH;
        const float4* x4 = (const float4*)x;
        for (int it = 0; it < 32; ++it) {
            const int g = bx * 8192 + it * 256 + tid;
            float4 v = x4[g];
            ushort4 o;
            o.x = f2bf(v.x); o.y = f2bf(v.y); o.z = f2bf(v.z); o.w = f2bf(v.w);
            ((ushort4*)xq)[g] = o;
        }
        return;
    }

    const float* wrow = w + (size_t)blockIdx.x * IN_CH;
    unsigned short* orow = wq + (size_t)blockIdx.x * IN_CH;

    __shared__ float s1_lds[64];
    __shared__ float s2_lds;

    float4 v[4];
    const int lane16 = tid & 15;

    // Pass A: per-64-block max|.| -> s1
    for (int p = 0; p < 4; ++p) {
        v[p] = ((const float4*)wrow)[p * 256 + tid];
        float m = fmaxf(fmaxf(fabsf(v[p].x), fabsf(v[p].y)),
                        fmaxf(fabsf(v[p].z), fabsf(v[p].w)));
        m = fmaxf(m, __shfl_xor(m, 1));
        m = fmaxf(m, __shfl_xor(m, 2));
        m = fmaxf(m, __shfl_xor(m, 4));
        m = fmaxf(m, __shfl_xor(m, 8));
        if (lane16 == 0)
            s1_lds[p * 16 + (tid >> 4)] = fmaxf(m * (1.0f / 7.0f), 1e-8f);
    }
    __syncthreads();

    // Pass B: s2 = clip(max_b s1 / 15, 1e-8)
    if (tid < 64) {
        float m = s1_lds[tid];
        m = fmaxf(m, __shfl_xor(m, 1));
        m = fmaxf(m, __shfl_xor(m, 2));
        m = fmaxf(m, __shfl_xor(m, 4));
        m = fmaxf(m, __shfl_xor(m, 8));
        m = fmaxf(m, __shfl_xor(m, 16));
        m = fmaxf(m, __shfl_xor(m, 32));
        if (tid == 0) s2_lds = fmaxf(m * (1.0f / 15.0f), 1e-8f);
    }
    __syncthreads();
    const float s2 = s2_lds;

    // Pass C: requantize exactly as reference (fp32 div + rintf)
    for (int p = 0; p < 4; ++p) {
        const float s1 = s1_lds[p * 16 + (tid >> 4)];
        const float s1q = fminf(fmaxf(rintf(s1 / s2), 0.0f), 15.0f);
        const float s1r = s1q * s2;
        ushort4 o;
        o.x = f2bf(fminf(fmaxf(rintf(v[p].x / s1r), -8.0f), 7.0f) * s1r);
        o.y = f2bf(fminf(fmaxf(rintf(v[p].y / s1r), -8.0f), 7.0f) * s1r);
        o.z = f2bf(fminf(fmaxf(rintf(v[p].z / s1r), -8.0f), 7.0f) * s1r);
        o.w = f2bf(fminf(fmaxf(rintf(v[p].w / s1r), -8.0f), 7.0f) * s1r);
        ((ushort4*)orow)[p * 256 + tid] = o;
    }
}

// ---------------------------------------------------------------------------
// Kernel 2: bf16 GEMM with K-split. part[s][m][n] = sum_{k in split s} A.B^T
// Grid: (NTILES, KSPLIT). 688 blocks -> ~2.7 blocks/CU for latency hiding.
// ---------------------------------------------------------------------------
__global__ __launch_bounds__(256) void gemm_kernel(
        const unsigned short* __restrict__ A, const unsigned short* __restrict__ B,
        float* __restrict__ part) {
    __shared__ __align__(16) unsigned short ldsA[BM * BK];  // 16 KB
    __shared__ __align__(16) unsigned short ldsB[BN * BK];  // 8 KB

    const int tid = threadIdx.x;
    const int w = tid >> 6;
    const int l = tid & 63;
    const int wm = w >> 1;
    const int wn = w & 1;
    const int n0 = blockIdx.x * BN;
    const int kc0 = blockIdx.y * SPLIT_CHUNKS;

    const int r8 = l >> 3;
    const int sg = l & 7;

    f32x4 acc[4][2] = {};

    const int lane15 = l & 15;
    const int quad = l >> 4;

    for (int kc = kc0; kc < kc0 + SPLIT_CHUNKS; ++kc) {
        const int k0 = kc * BK;

        for (int i = 0; i < 4; ++i) {
            const int r = i * 32 + w * 8 + r8;
            const unsigned short* gp = A + (size_t)r * IN_CH + k0 + sg * 8;
            LDS_AS unsigned short* lp =
                (LDS_AS unsigned short*)&ldsA[(i * 32 + w * 8) * BK];
            __builtin_amdgcn_global_load_lds((const GLOBAL_AS void*)gp,
                                             (LDS_AS void*)lp, 16, 0, 0);
        }
        for (int j = 0; j < 2; ++j) {
            const int r = j * 32 + w * 8 + r8;
            const unsigned short* gp = B + (size_t)(n0 + r) * IN_CH + k0 + sg * 8;
            LDS_AS unsigned short* lp =
                (LDS_AS unsigned short*)&ldsB[(j * 32 + w * 8) * BK];
            __builtin_amdgcn_global_load_lds((const GLOBAL_AS void*)gp,
                                             (LDS_AS void*)lp, 16, 0, 0);
        }
        asm volatile("s_waitcnt vmcnt(0)" ::: "memory");
        __syncthreads();

        for (int kk = 0; kk < 2; ++kk) {
            bf16x8 af[4], bfv[2];
            const int ko = kk * 32 + quad * 8;
            for (int i = 0; i < 4; ++i)
                af[i] = *(const bf16x8*)&ldsA[(wm * 64 + i * 16 + lane15) * BK + ko];
            for (int j = 0; j < 2; ++j)
                bfv[j] = *(const bf16x8*)&ldsB[(wn * 32 + j * 16 + lane15) * BK + ko];
            for (int i = 0; i < 4; ++i)
                for (int j = 0; j < 2; ++j)
                    acc[i][j] = __builtin_amdgcn_mfma_f32_16x16x32_bf16(
                        af[i], bfv[j], acc[i][j], 0, 0, 0);
        }
        __syncthreads();
    }

    // epilogue: partial store (no bias), C/D layout col=lane&15, row=quad*4+reg
    float* pbase = part + (size_t)blockIdx.y * BM * OUT_CH;
    const int m_base = wm * 64 + quad * 4;
    const int n_base = n0 + wn * 32 + lane15;
    for (int j = 0; j < 2; ++j) {
        for (int i = 0; i < 4; ++i) {
            const int m = m_base + i * 16;
            float* cp = pbase + (size_t)m * OUT_CH + n_base + j * 16;
            cp[0 * OUT_CH] = acc[i][j][0];
            cp[1 * OUT_CH] = acc[i][j][1];
            cp[2 * OUT_CH] = acc[i][j][2];
            cp[3 * OUT_CH] = acc[i][j][3];
        }
    }
}

// ---------------------------------------------------------------------------
// Kernel 3: reduce K-split partials + bias. Grid (11, 128) x 256 thr, float4.
// ---------------------------------------------------------------------------
__global__ __launch_bounds__(256) void reduce_kernel(
        const float* __restrict__ part, const float* __restrict__ bias,
        float* __restrict__ out) {
    const int m = blockIdx.y;
    const int x4 = blockIdx.x * 256 + threadIdx.x;   // float4 index in row
    if (x4 >= OUT_CH / 4) return;
    const size_t off = (size_t)m * OUT_CH + x4 * 4;

    float4 acc = ((const float4*)bias)[x4];
    for (int s = 0; s < KSPLIT; ++s) {
        float4 p = *(const float4*)(part + (size_t)s * BM * OUT_CH + off);
        acc.x += p.x; acc.y += p.y; acc.z += p.z; acc.w += p.w;
    }
    *(float4*)(out + off) = acc;
}

extern "C" void kernel_launch(void* const* d_in, const int* in_sizes, int n_in,
                              void* d_out, int out_size, void* d_ws, size_t ws_size,
                              hipStream_t stream) {
    const float* x = (const float*)d_in[0];       // (1,128,4096) fp32
    const float* weight = (const float*)d_in[1];  // (11008,4096) fp32
    const float* bias = (const float*)d_in[2];    // (11008,) fp32
    float* out = (float*)d_out;                   // (1,128,11008) fp32

    unsigned short* wsW = (unsigned short*)d_ws;                  // 90.2 MB bf16 w_recon
    unsigned short* wsX = wsW + (size_t)OUT_CH * IN_CH;           // 1 MB bf16 x
    float* wsP = (float*)(wsX + (size_t)BM * IN_CH);              // 22.5 MB partials

    quant_kernel<<<OUT_CH + XCONV_BLOCKS, 256, 0, stream>>>(weight, x, wsW, wsX);
    gemm_kernel<<<dim3(NTILES, KSPLIT), 256, 0, stream>>>(wsX, wsW, wsP);
    reduce_kernel<<<dim3((OUT_CH / 4 + 255) / 256, BM), 256, 0, stream>>>(
        wsP, bias, out);
}

// Round 3
// 297.704 us; speedup vs baseline: 1.1079x; 1.0103x over previous
//
#include <hip/hip_runtime.h>
#include <hip/hip_bf16.h>

#define IN_CH 4096
#define OUT_CH 11008
#define QBLK 64

#define BM 128
#define BN 64
#define BK 64
#define KCHUNKS (IN_CH / BK)            // 64
#define KSPLIT 4
#define SPLIT_CHUNKS (KCHUNKS / KSPLIT) // 16
#define NTILES (OUT_CH / BN)            // 172
#define XCONV_BLOCKS 16
#define BPAD 72                          // B LDS row stride (64 + 8 pad)

typedef short bf16x8 __attribute__((ext_vector_type(8)));
typedef float f32x4 __attribute__((ext_vector_type(4)));
typedef char char16v __attribute__((ext_vector_type(16)));

#define GLOBAL_AS __attribute__((address_space(1)))
#define LDS_AS __attribute__((address_space(3)))

__device__ inline unsigned short f2bf(float f) {
    union { __hip_bfloat16 h; unsigned short u; } cv;
    cv.h = __float2bfloat16(f);
    return cv.u;
}

// ---------------------------------------------------------------------------
// Kernel 1: LPBQ quantize of weight -> int8 w_q (45 MB) + fp32 s1r transposed
// [kblock][row] (2.8 MB). Blocks [OUT_CH, OUT_CH+16) convert x -> bf16.
// w_recon is NOT materialized; GEMM reconstructs float(w_q)*s1r -> bf16,
// bit-identical to materializing bf16 here.
// ---------------------------------------------------------------------------
__global__ __launch_bounds__(256) void quant_kernel(
        const float* __restrict__ w, const float* __restrict__ x,
        signed char* __restrict__ wq, float* __restrict__ s1rT,
        unsigned short* __restrict__ xq) {
    const int tid = threadIdx.x;

    if (blockIdx.x >= OUT_CH) {
        // ---- x fp32 -> bf16 (128*4096 el = 131072 float4) ----
        const int bx = blockIdx.x - OUT_CH;
        const float4* x4 = (const float4*)x;
        for (int it = 0; it < 32; ++it) {
            const int g = bx * 8192 + it * 256 + tid;
            float4 v = x4[g];
            ushort4 o;
            o.x = f2bf(v.x); o.y = f2bf(v.y); o.z = f2bf(v.z); o.w = f2bf(v.w);
            ((ushort4*)xq)[g] = o;
        }
        return;
    }

    const int row = blockIdx.x;
    const float* wrow = w + (size_t)row * IN_CH;
    signed char* orow = wq + (size_t)row * IN_CH;

    __shared__ float s1_lds[64];   // pass A: s1; after pass B: s1r
    __shared__ float s2_lds;

    float4 v[4];
    const int lane16 = tid & 15;

    // Pass A: per-64-block max|.| -> s1 (16 lanes per quant-block)
    for (int p = 0; p < 4; ++p) {
        v[p] = ((const float4*)wrow)[p * 256 + tid];
        float m = fmaxf(fmaxf(fabsf(v[p].x), fabsf(v[p].y)),
                        fmaxf(fabsf(v[p].z), fabsf(v[p].w)));
        m = fmaxf(m, __shfl_xor(m, 1));
        m = fmaxf(m, __shfl_xor(m, 2));
        m = fmaxf(m, __shfl_xor(m, 4));
        m = fmaxf(m, __shfl_xor(m, 8));
        if (lane16 == 0)
            s1_lds[p * 16 + (tid >> 4)] = fmaxf(m * (1.0f / 7.0f), 1e-8f);
    }
    __syncthreads();

    // Pass B: s2 = clip(max_b s1 / 15, 1e-8); then s1r = clip(rint(s1/s2))*s2
    if (tid < 64) {
        float s1 = s1_lds[tid];
        float m = s1;
        m = fmaxf(m, __shfl_xor(m, 1));
        m = fmaxf(m, __shfl_xor(m, 2));
        m = fmaxf(m, __shfl_xor(m, 4));
        m = fmaxf(m, __shfl_xor(m, 8));
        m = fmaxf(m, __shfl_xor(m, 16));
        m = fmaxf(m, __shfl_xor(m, 32));
        const float s2 = fmaxf(m * (1.0f / 15.0f), 1e-8f);
        const float s1q = fminf(fmaxf(rintf(s1 / s2), 0.0f), 15.0f);
        const float s1r = s1q * s2;
        s1_lds[tid] = s1r;
        s1rT[(size_t)tid * OUT_CH + row] = s1r;   // transposed scale store
    }
    __syncthreads();

    // Pass C: w_q = clip(rint(w / s1r), -8, 7) stored int8
    // (NaN/inf from s1r==0 are clamped in float before the int cast)
    for (int p = 0; p < 4; ++p) {
        const float s1r = s1_lds[p * 16 + (tid >> 4)];
        char4 o;
        o.x = (signed char)(int)fminf(fmaxf(rintf(v[p].x / s1r), -8.0f), 7.0f);
        o.y = (signed char)(int)fminf(fmaxf(rintf(v[p].y / s1r), -8.0f), 7.0f);
        o.z = (signed char)(int)fminf(fmaxf(rintf(v[p].z / s1r), -8.0f), 7.0f);
        o.w = (signed char)(int)fminf(fmaxf(rintf(v[p].w / s1r), -8.0f), 7.0f);
        ((char4*)orow)[p * 256 + tid] = o;
    }
}

// ---------------------------------------------------------------------------
// Kernel 2: K-split GEMM with fused int8 -> bf16 dequant of B.
// A (x bf16) staged via global_load_lds w=16; B staged via registers:
// load 16 int8, w = float(q)*s1r -> bf16, ds_write_b128 x2 (2-way banks).
// part[s][m][n] = sum_{k in split s} A.B^T
// ---------------------------------------------------------------------------
__global__ __launch_bounds__(256) void gemm_kernel(
        const unsigned short* __restrict__ A, const signed char* __restrict__ WQ,
        const float* __restrict__ s1rT, float* __restrict__ part) {
    __shared__ __align__(16) unsigned short ldsA[BM * BK];   // 16 KB
    __shared__ __align__(16) unsigned short ldsB[BN * BPAD]; // 9 KB, padded

    const int tid = threadIdx.x;
    const int w = tid >> 6;
    const int l = tid & 63;
    const int wm = w >> 1;
    const int wn = w & 1;
    const int n0 = blockIdx.x * BN;
    const int kc0 = blockIdx.y * SPLIT_CHUNKS;

    const int r8 = l >> 3;       // A staging: row within 8-row group
    const int sg = l & 7;        // A staging: 16B segment in 128B row

    const int brow = tid >> 2;   // B staging: row 0..63 (4 thr/row)
    const int bcg = tid & 3;     // B staging: 16-el col group

    f32x4 acc[4][2] = {};

    const int lane15 = l & 15;
    const int quad = l >> 4;

    for (int kc = kc0; kc < kc0 + SPLIT_CHUNKS; ++kc) {
        const int k0 = kc * BK;

        // ---- A tile: async global -> LDS (stays in flight) ----
        for (int i = 0; i < 4; ++i) {
            const unsigned short* gp =
                A + (size_t)(i * 32 + w * 8 + r8) * IN_CH + k0 + sg * 8;
            LDS_AS unsigned short* lp =
                (LDS_AS unsigned short*)&ldsA[(i * 32 + w * 8) * BK];
            __builtin_amdgcn_global_load_lds((const GLOBAL_AS void*)gp,
                                             (LDS_AS void*)lp, 16, 0, 0);
        }

        // ---- B tile: int8 load -> dequant -> LDS bf16 ----
        const float s1 = s1rT[(size_t)kc * OUT_CH + n0 + brow];
        char16v bq = *(const char16v*)(WQ + (size_t)(n0 + brow) * IN_CH +
                                       k0 + bcg * 16);
        bf16x8 o0, o1;
        for (int i = 0; i < 8; ++i)
            o0[i] = (short)f2bf((float)bq[i] * s1);
        for (int i = 0; i < 8; ++i)
            o1[i] = (short)f2bf((float)bq[8 + i] * s1);
        *(bf16x8*)&ldsB[brow * BPAD + bcg * 16] = o0;
        *(bf16x8*)&ldsB[brow * BPAD + bcg * 16 + 8] = o1;

        asm volatile("s_waitcnt vmcnt(0)" ::: "memory");
        __syncthreads();

        // ---- MFMA over the 64-deep chunk ----
        for (int kk = 0; kk < 2; ++kk) {
            bf16x8 af[4], bfv[2];
            const int ko = kk * 32 + quad * 8;
            for (int i = 0; i < 4; ++i)
                af[i] = *(const bf16x8*)&ldsA[(wm * 64 + i * 16 + lane15) * BK + ko];
            for (int j = 0; j < 2; ++j)
                bfv[j] = *(const bf16x8*)&ldsB[(wn * 32 + j * 16 + lane15) * BPAD + ko];
            for (int i = 0; i < 4; ++i)
                for (int j = 0; j < 2; ++j)
                    acc[i][j] = __builtin_amdgcn_mfma_f32_16x16x32_bf16(
                        af[i], bfv[j], acc[i][j], 0, 0, 0);
        }
        __syncthreads();
    }

    // ---- epilogue: partial store, C/D layout col=lane&15, row=quad*4+reg ----
    float* pbase = part + (size_t)blockIdx.y * BM * OUT_CH;
    const int m_base = wm * 64 + quad * 4;
    const int n_base = n0 + wn * 32 + lane15;
    for (int j = 0; j < 2; ++j) {
        for (int i = 0; i < 4; ++i) {
            const int m = m_base + i * 16;
            float* cp = pbase + (size_t)m * OUT_CH + n_base + j * 16;
            cp[0 * OUT_CH] = acc[i][j][0];
            cp[1 * OUT_CH] = acc[i][j][1];
            cp[2 * OUT_CH] = acc[i][j][2];
            cp[3 * OUT_CH] = acc[i][j][3];
        }
    }
}

// ---------------------------------------------------------------------------
// Kernel 3: reduce K-split partials + bias. Grid (11, 128) x 256 thr, float4.
// ---------------------------------------------------------------------------
__global__ __launch_bounds__(256) void reduce_kernel(
        const float* __restrict__ part, const float* __restrict__ bias,
        float* __restrict__ out) {
    const int m = blockIdx.y;
    const int x4 = blockIdx.x * 256 + threadIdx.x;
    if (x4 >= OUT_CH / 4) return;
    const size_t off = (size_t)m * OUT_CH + x4 * 4;

    float4 acc = ((const float4*)bias)[x4];
    for (int s = 0; s < KSPLIT; ++s) {
        float4 p = *(const float4*)(part + (size_t)s * BM * OUT_CH + off);
        acc.x += p.x; acc.y += p.y; acc.z += p.z; acc.w += p.w;
    }
    *(float4*)(out + off) = acc;
}

extern "C" void kernel_launch(void* const* d_in, const int* in_sizes, int n_in,
                              void* d_out, int out_size, void* d_ws, size_t ws_size,
                              hipStream_t stream) {
    const float* x = (const float*)d_in[0];       // (1,128,4096) fp32
    const float* weight = (const float*)d_in[1];  // (11008,4096) fp32
    const float* bias = (const float*)d_in[2];    // (11008,) fp32
    float* out = (float*)d_out;                   // (1,128,11008) fp32

    // workspace layout (16B-aligned slices)
    signed char* wsQ = (signed char*)d_ws;                        // 45.1 MB int8 w_q
    unsigned short* wsX = (unsigned short*)(wsQ + (size_t)OUT_CH * IN_CH); // 1 MB bf16 x
    float* wsS = (float*)(wsX + (size_t)BM * IN_CH);              // 2.8 MB s1r^T
    float* wsP = wsS + (size_t)QBLK * OUT_CH;                     // 22.5 MB partials

    quant_kernel<<<OUT_CH + XCONV_BLOCKS, 256, 0, stream>>>(weight, x, wsQ, wsS, wsX);
    gemm_kernel<<<dim3(NTILES, KSPLIT), 256, 0, stream>>>(wsX, wsQ, wsS, wsP);
    reduce_kernel<<<dim3((OUT_CH / 4 + 255) / 256, BM), 256, 0, stream>>>(
        wsP, bias, out);
}